// Round 1
// baseline (1307.023 us; speedup 1.0000x reference)
//
#include <hip/hip_runtime.h>
#include <cfloat>

#define N_ROWS 65536
#define DIM 256
#define K_CODES 2048
#define MT 64      // rows per block
#define KT 256     // codes per k-tile
#define DC 16      // d-chunk staged in LDS
#define BLOCK 256
#define ZSTR 68    // padded row stride for zS (floats)

// ---------------- e_sq precompute: one wave per code ----------------
__global__ __launch_bounds__(256)
void vq_esq_kernel(const float* __restrict__ emb, float* __restrict__ esq) {
    int w = threadIdx.x >> 6;
    int lane = threadIdx.x & 63;
    int k = blockIdx.x * 4 + w;
    float4 v = *(const float4*)&emb[(size_t)k * DIM + lane * 4];
    float s = v.x * v.x + v.y * v.y + v.z * v.z + v.w * v.w;
    #pragma unroll
    for (int off = 32; off >= 1; off >>= 1) s += __shfl_xor(s, off, 64);
    if (lane == 0) esq[k] = s;
}

// ---------------- main fused kernel ----------------
// Block handles MT=64 rows. Loops k-tiles of KT=256 codes; for each k-tile
// accumulates the full 256-d dot in 8x8 per-thread register tiles, then does
// the literal f32 distance + running argmin (lowest index on ties, matching
// np.argmin). Epilogue gathers z_q, writes z_q_st, loss partial, indices.
__global__ __launch_bounds__(BLOCK, 4)
void vq_main_kernel(const float* __restrict__ z,
                    const float* __restrict__ emb,
                    const float* __restrict__ esq,
                    float* __restrict__ out,
                    float* __restrict__ loss_acc) {
    __shared__ float zS[DC][ZSTR];     // [d][row], padded stride
    __shared__ float eT[DC][KT];       // [d][code]
    __shared__ float zsq_s[MT];
    __shared__ int   best_s[MT];
    __shared__ float lred[4];

    const int tid = threadIdx.x;
    const int m0  = blockIdx.x * MT;
    const int rg  = tid >> 5;   // 0..7  : owns rows 8*rg .. 8*rg+7
    const int cg  = tid & 31;   // 0..31 : owns codes 8*cg .. 8*cg+7 (within k-tile)

    // ---- z_sq for the block's 64 rows (4 threads per row) ----
    {
        int r = tid >> 2;
        int q = tid & 3;
        const float* zr = &z[(size_t)(m0 + r) * DIM + q * 64];
        float s = 0.f;
        #pragma unroll
        for (int d4 = 0; d4 < 16; ++d4) {
            float4 v = *(const float4*)&zr[d4 * 4];
            s += v.x * v.x; s += v.y * v.y; s += v.z * v.z; s += v.w * v.w;
        }
        s += __shfl_down(s, 2, 64);
        s += __shfl_down(s, 1, 64);
        if (q == 0) zsq_s[r] = s;
    }
    __syncthreads();

    float bestv[8];
    int   besti[8];
    #pragma unroll
    for (int j = 0; j < 8; ++j) { bestv[j] = FLT_MAX; besti[j] = 0; }

    for (int kt = 0; kt < K_CODES; kt += KT) {
        float acc[8][8];
        #pragma unroll
        for (int j = 0; j < 8; ++j)
            #pragma unroll
            for (int i = 0; i < 8; ++i) acc[j][i] = 0.f;

        for (int dc = 0; dc < DIM; dc += DC) {
            __syncthreads();
            // stage z chunk: 64 rows x 16 d (transposed into zS)
            {
                int r = tid >> 2, f = tid & 3;
                float4 v = *(const float4*)&z[(size_t)(m0 + r) * DIM + dc + 4 * f];
                zS[4 * f + 0][r] = v.x;
                zS[4 * f + 1][r] = v.y;
                zS[4 * f + 2][r] = v.z;
                zS[4 * f + 3][r] = v.w;
            }
            // stage emb chunk: 256 codes x 16 d (transposed into eT)
            {
                int f = tid & 3;
                #pragma unroll
                for (int cb = 0; cb < 4; ++cb) {
                    int c = (tid >> 2) + cb * 64;
                    float4 v = *(const float4*)&emb[(size_t)(kt + c) * DIM + dc + 4 * f];
                    eT[4 * f + 0][c] = v.x;
                    eT[4 * f + 1][c] = v.y;
                    eT[4 * f + 2][c] = v.z;
                    eT[4 * f + 3][c] = v.w;
                }
            }
            __syncthreads();
            #pragma unroll
            for (int d = 0; d < DC; ++d) {
                float4 a0 = *(const float4*)&zS[d][8 * rg];
                float4 a1 = *(const float4*)&zS[d][8 * rg + 4];
                float4 b0 = *(const float4*)&eT[d][8 * cg];
                float4 b1 = *(const float4*)&eT[d][8 * cg + 4];
                float a[8] = {a0.x, a0.y, a0.z, a0.w, a1.x, a1.y, a1.z, a1.w};
                float b[8] = {b0.x, b0.y, b0.z, b0.w, b1.x, b1.y, b1.z, b1.w};
                #pragma unroll
                for (int j = 0; j < 8; ++j)
                    #pragma unroll
                    for (int i = 0; i < 8; ++i)
                        acc[j][i] = fmaf(a[j], b[i], acc[j][i]);
            }
        }
        // literal f32 distance + running argmin (ascending k => lowest-index ties)
        float4 e0 = *(const float4*)&esq[kt + 8 * cg];
        float4 e1 = *(const float4*)&esq[kt + 8 * cg + 4];
        float es[8] = {e0.x, e0.y, e0.z, e0.w, e1.x, e1.y, e1.z, e1.w};
        #pragma unroll
        for (int j = 0; j < 8; ++j) {
            float zs = zsq_s[8 * rg + j];
            #pragma unroll
            for (int i = 0; i < 8; ++i) {
                float t    = zs + es[i];               // fl(z_sq + e_sq)
                float dist = t - 2.0f * acc[j][i];     // fl(t - 2*cross)
                int   idx  = kt + 8 * cg + i;
                bool better = (dist < bestv[j]);
                bestv[j] = better ? dist : bestv[j];
                besti[j] = better ? idx  : besti[j];
            }
        }
    }

    // cross-lane argmin over the 32 code-group lanes (lexicographic: val, then idx)
    #pragma unroll
    for (int off = 16; off >= 1; off >>= 1) {
        #pragma unroll
        for (int j = 0; j < 8; ++j) {
            float ov = __shfl_xor(bestv[j], off, 64);
            int   oi = __shfl_xor(besti[j], off, 64);
            bool take = (ov < bestv[j]) || (ov == bestv[j] && oi < besti[j]);
            bestv[j] = take ? ov : bestv[j];
            besti[j] = take ? oi : besti[j];
        }
    }
    if (cg == 0) {
        #pragma unroll
        for (int j = 0; j < 8; ++j) best_s[8 * rg + j] = besti[j];
    }
    __syncthreads();

    // ---- epilogue: z_q_st (straight-through), loss partial, indices ----
    float lsum = 0.f;
    const int d4 = tid & 63;
    for (int it = 0; it < 16; ++it) {
        int r  = (tid >> 6) + it * 4;
        int bk = best_s[r];
        float4 q4 = *(const float4*)&emb[(size_t)bk * DIM + 4 * d4];
        float4 z4 = *(const float4*)&z[(size_t)(m0 + r) * DIM + 4 * d4];
        float4 o;
        float dx;
        dx = q4.x - z4.x; o.x = z4.x + dx; lsum = fmaf(dx, dx, lsum);
        dx = q4.y - z4.y; o.y = z4.y + dx; lsum = fmaf(dx, dx, lsum);
        dx = q4.z - z4.z; o.z = z4.z + dx; lsum = fmaf(dx, dx, lsum);
        dx = q4.w - z4.w; o.w = z4.w + dx; lsum = fmaf(dx, dx, lsum);
        *(float4*)&out[(size_t)(m0 + r) * DIM + 4 * d4] = o;
    }
    #pragma unroll
    for (int off = 32; off >= 1; off >>= 1) lsum += __shfl_xor(lsum, off, 64);
    if ((tid & 63) == 0) lred[tid >> 6] = lsum;
    __syncthreads();
    if (tid == 0) {
        float bs = lred[0] + lred[1] + lred[2] + lred[3];
        atomicAdd(loss_acc, bs);
    }
    // indices as float32 values
    if (tid < MT) out[(size_t)N_ROWS * DIM + 1 + m0 + tid] = (float)best_s[tid];
}

// ---------------- finalize: vq_loss = 1.25 * mean ----------------
__global__ void vq_finalize_kernel(const float* __restrict__ loss_acc,
                                   float* __restrict__ out) {
    double s = (double)loss_acc[0];
    out[(size_t)N_ROWS * DIM] = (float)(s * 1.25 / ((double)N_ROWS * (double)DIM));
}

extern "C" void kernel_launch(void* const* d_in, const int* in_sizes, int n_in,
                              void* d_out, int out_size, void* d_ws, size_t ws_size,
                              hipStream_t stream) {
    (void)in_sizes; (void)n_in; (void)out_size; (void)ws_size;
    const float* z   = (const float*)d_in[0];
    const float* emb = (const float*)d_in[1];
    float* out = (float*)d_out;
    float* ws  = (float*)d_ws;
    float* loss_acc = ws;        // ws[0]
    float* esq      = ws + 64;   // 2048 floats, 256B-aligned offset

    hipMemsetAsync(d_ws, 0, sizeof(float), stream);
    vq_esq_kernel<<<K_CODES / 4, 256, 0, stream>>>(emb, esq);
    vq_main_kernel<<<N_ROWS / MT, BLOCK, 0, stream>>>(z, emb, esq, out, loss_acc);
    vq_finalize_kernel<<<1, 1, 0, stream>>>(loss_acc, out);
}

// Round 2
// 1031.719 us; speedup vs baseline: 1.2668x; 1.2668x over previous
//
#include <hip/hip_runtime.h>
#include <cfloat>

#define N_ROWS 65536
#define DIM 256
#define K_CODES 2048
#define MT 64      // rows per block
#define KT 256     // codes per k-tile
#define DC 16      // d-chunk staged in LDS
#define BLOCK 256
#define ZSTR 68            // padded row stride for zS (floats)
#define ESTR (KT + 4)      // padded row stride for eT (floats, 16B-mult keeps b128 align)
#define NSTAGES ((DIM / DC) * (K_CODES / KT))   // 128

// ---------------- e_sq precompute: one wave per code ----------------
__global__ __launch_bounds__(256)
void vq_esq_kernel(const float* __restrict__ emb, float* __restrict__ esq) {
    int w = threadIdx.x >> 6;
    int lane = threadIdx.x & 63;
    int k = blockIdx.x * 4 + w;
    float4 v = *(const float4*)&emb[(size_t)k * DIM + lane * 4];
    float s = v.x * v.x + v.y * v.y + v.z * v.z + v.w * v.w;
    #pragma unroll
    for (int off = 32; off >= 1; off >>= 1) s += __shfl_xor(s, off, 64);
    if (lane == 0) esq[k] = s;
}

// ---------------- main fused kernel (conflict-free, double-buffered) --------
// Thread (rg,cg) owns rows {8rg..8rg+7} x codes {kt+4cg+i} u {kt+128+4cg+i}.
// eT reads are lane-contiguous b128 (conflict-free); zS reads broadcast.
// One barrier per stage; global prefetch for stage s+1 issued before the
// 1024-FMA compute of stage s, LDS writes after.
__global__ __launch_bounds__(BLOCK, 3)
void vq_main_kernel(const float* __restrict__ z,
                    const float* __restrict__ emb,
                    const float* __restrict__ esq,
                    float* __restrict__ out,
                    float* __restrict__ loss_acc) {
    __shared__ float zS[2][DC][ZSTR];
    __shared__ float eT[2][DC][ESTR];
    __shared__ float zsq_s[MT];
    __shared__ int   best_s[MT];
    __shared__ float lred[4];

    const int tid = threadIdx.x;
    const int m0  = blockIdx.x * MT;
    const int rg  = tid >> 5;   // 0..7  : rows 8*rg..8*rg+7
    const int cg  = tid & 31;   // 0..31 : codes 4*cg(+128)
    const int sr  = tid >> 2;   // staging row / code-base (0..63)
    const int sf  = tid & 3;    // staging float4 slot in d-chunk

    // ---- z_sq for the block's 64 rows (4 threads per row) ----
    {
        const float* zr = &z[(size_t)(m0 + sr) * DIM + sf * 64];
        float s = 0.f;
        #pragma unroll
        for (int d4 = 0; d4 < 16; ++d4) {
            float4 v = *(const float4*)&zr[d4 * 4];
            s += v.x * v.x; s += v.y * v.y; s += v.z * v.z; s += v.w * v.w;
        }
        s += __shfl_down(s, 2, 64);
        s += __shfl_down(s, 1, 64);
        if (sf == 0) zsq_s[sr] = s;
    }

    // ---- stage 0 into buffer 0 ----
    {
        float4 zv = *(const float4*)&z[(size_t)(m0 + sr) * DIM + 4 * sf];
        zS[0][4 * sf + 0][sr] = zv.x;
        zS[0][4 * sf + 1][sr] = zv.y;
        zS[0][4 * sf + 2][sr] = zv.z;
        zS[0][4 * sf + 3][sr] = zv.w;
        #pragma unroll
        for (int cb = 0; cb < 4; ++cb) {
            int c = sr + cb * 64;
            float4 ev = *(const float4*)&emb[(size_t)c * DIM + 4 * sf];
            eT[0][4 * sf + 0][c] = ev.x;
            eT[0][4 * sf + 1][c] = ev.y;
            eT[0][4 * sf + 2][c] = ev.z;
            eT[0][4 * sf + 3][c] = ev.w;
        }
    }
    __syncthreads();

    float bestv[8];
    int   besti[8];
    #pragma unroll
    for (int j = 0; j < 8; ++j) { bestv[j] = FLT_MAX; besti[j] = 0; }

    float acc[8][8];

    for (int s = 0; s < NSTAGES; ++s) {
        const int p     = s & 1;
        const int kt    = (s >> 4) * KT;
        const int dcIdx = s & 15;

        if (dcIdx == 0) {
            #pragma unroll
            for (int j = 0; j < 8; ++j)
                #pragma unroll
                for (int i = 0; i < 8; ++i) acc[j][i] = 0.f;
        }

        // ---- prefetch stage s+1 (global -> regs); uniform clamp on last ----
        const int sn  = (s + 1 < NSTAGES) ? s + 1 : s;
        const int nkt = (sn >> 4) * KT;
        const int ndc = (sn & 15) * DC;
        float4 zn = *(const float4*)&z[(size_t)(m0 + sr) * DIM + ndc + 4 * sf];
        float4 en0 = *(const float4*)&emb[(size_t)(nkt + sr +   0) * DIM + ndc + 4 * sf];
        float4 en1 = *(const float4*)&emb[(size_t)(nkt + sr +  64) * DIM + ndc + 4 * sf];
        float4 en2 = *(const float4*)&emb[(size_t)(nkt + sr + 128) * DIM + ndc + 4 * sf];
        float4 en3 = *(const float4*)&emb[(size_t)(nkt + sr + 192) * DIM + ndc + 4 * sf];

        // ---- compute stage s ----
        #pragma unroll
        for (int d = 0; d < DC; ++d) {
            float4 a0 = *(const float4*)&zS[p][d][8 * rg];
            float4 a1 = *(const float4*)&zS[p][d][8 * rg + 4];
            float4 b0 = *(const float4*)&eT[p][d][4 * cg];
            float4 b1 = *(const float4*)&eT[p][d][128 + 4 * cg];
            float a[8] = {a0.x, a0.y, a0.z, a0.w, a1.x, a1.y, a1.z, a1.w};
            float b[8] = {b0.x, b0.y, b0.z, b0.w, b1.x, b1.y, b1.z, b1.w};
            #pragma unroll
            for (int j = 0; j < 8; ++j)
                #pragma unroll
                for (int i = 0; i < 8; ++i)
                    acc[j][i] = fmaf(a[j], b[i], acc[j][i]);
        }

        // ---- write prefetched stage into the other buffer ----
        {
            const int q = p ^ 1;
            zS[q][4 * sf + 0][sr] = zn.x;
            zS[q][4 * sf + 1][sr] = zn.y;
            zS[q][4 * sf + 2][sr] = zn.z;
            zS[q][4 * sf + 3][sr] = zn.w;
            eT[q][4 * sf + 0][sr      ] = en0.x;
            eT[q][4 * sf + 1][sr      ] = en0.y;
            eT[q][4 * sf + 2][sr      ] = en0.z;
            eT[q][4 * sf + 3][sr      ] = en0.w;
            eT[q][4 * sf + 0][sr +  64] = en1.x;
            eT[q][4 * sf + 1][sr +  64] = en1.y;
            eT[q][4 * sf + 2][sr +  64] = en1.z;
            eT[q][4 * sf + 3][sr +  64] = en1.w;
            eT[q][4 * sf + 0][sr + 128] = en2.x;
            eT[q][4 * sf + 1][sr + 128] = en2.y;
            eT[q][4 * sf + 2][sr + 128] = en2.z;
            eT[q][4 * sf + 3][sr + 128] = en2.w;
            eT[q][4 * sf + 0][sr + 192] = en3.x;
            eT[q][4 * sf + 1][sr + 192] = en3.y;
            eT[q][4 * sf + 2][sr + 192] = en3.z;
            eT[q][4 * sf + 3][sr + 192] = en3.w;
        }

        // ---- end of k-tile: literal f32 distance + running argmin ----
        if (dcIdx == 15) {
            float4 e0 = *(const float4*)&esq[kt + 4 * cg];
            float4 e1 = *(const float4*)&esq[kt + 128 + 4 * cg];
            float es[8] = {e0.x, e0.y, e0.z, e0.w, e1.x, e1.y, e1.z, e1.w};
            #pragma unroll
            for (int j = 0; j < 8; ++j) {
                float zs = zsq_s[8 * rg + j];
                #pragma unroll
                for (int i = 0; i < 8; ++i) {
                    float t    = zs + es[i];             // fl(z_sq + e_sq)
                    float dist = t - 2.0f * acc[j][i];   // fl(t - 2*cross)
                    int idx = (i < 4) ? (kt + 4 * cg + i) : (kt + 128 + 4 * cg + (i - 4));
                    bool better = (dist < bestv[j]);
                    bestv[j] = better ? dist : bestv[j];
                    besti[j] = better ? idx  : besti[j];
                }
            }
        }
        __syncthreads();
    }

    // cross-lane argmin over the 32 code-group lanes (lexicographic: val, idx)
    #pragma unroll
    for (int off = 16; off >= 1; off >>= 1) {
        #pragma unroll
        for (int j = 0; j < 8; ++j) {
            float ov = __shfl_xor(bestv[j], off, 64);
            int   oi = __shfl_xor(besti[j], off, 64);
            bool take = (ov < bestv[j]) || (ov == bestv[j] && oi < besti[j]);
            bestv[j] = take ? ov : bestv[j];
            besti[j] = take ? oi : besti[j];
        }
    }
    if (cg == 0) {
        #pragma unroll
        for (int j = 0; j < 8; ++j) best_s[8 * rg + j] = besti[j];
    }
    __syncthreads();

    // ---- epilogue: z_q_st (straight-through), loss partial, indices ----
    float lsum = 0.f;
    const int d4 = tid & 63;
    for (int it = 0; it < 16; ++it) {
        int r  = (tid >> 6) + it * 4;
        int bk = best_s[r];
        float4 q4 = *(const float4*)&emb[(size_t)bk * DIM + 4 * d4];
        float4 z4 = *(const float4*)&z[(size_t)(m0 + r) * DIM + 4 * d4];
        float4 o;
        float dx;
        dx = q4.x - z4.x; o.x = z4.x + dx; lsum = fmaf(dx, dx, lsum);
        dx = q4.y - z4.y; o.y = z4.y + dx; lsum = fmaf(dx, dx, lsum);
        dx = q4.z - z4.z; o.z = z4.z + dx; lsum = fmaf(dx, dx, lsum);
        dx = q4.w - z4.w; o.w = z4.w + dx; lsum = fmaf(dx, dx, lsum);
        *(float4*)&out[(size_t)(m0 + r) * DIM + 4 * d4] = o;
    }
    #pragma unroll
    for (int off = 32; off >= 1; off >>= 1) lsum += __shfl_xor(lsum, off, 64);
    if ((tid & 63) == 0) lred[tid >> 6] = lsum;
    __syncthreads();
    if (tid == 0) {
        float bs = lred[0] + lred[1] + lred[2] + lred[3];
        atomicAdd(loss_acc, bs);
    }
    // indices as float32 values
    if (tid < MT) out[(size_t)N_ROWS * DIM + 1 + m0 + tid] = (float)best_s[tid];
}

// ---------------- finalize: vq_loss = 1.25 * mean ----------------
__global__ void vq_finalize_kernel(const float* __restrict__ loss_acc,
                                   float* __restrict__ out) {
    double s = (double)loss_acc[0];
    out[(size_t)N_ROWS * DIM] = (float)(s * 1.25 / ((double)N_ROWS * (double)DIM));
}

extern "C" void kernel_launch(void* const* d_in, const int* in_sizes, int n_in,
                              void* d_out, int out_size, void* d_ws, size_t ws_size,
                              hipStream_t stream) {
    (void)in_sizes; (void)n_in; (void)out_size; (void)ws_size;
    const float* z   = (const float*)d_in[0];
    const float* emb = (const float*)d_in[1];
    float* out = (float*)d_out;
    float* ws  = (float*)d_ws;
    float* loss_acc = ws;        // ws[0]
    float* esq      = ws + 64;   // 2048 floats

    hipMemsetAsync(d_ws, 0, sizeof(float), stream);
    vq_esq_kernel<<<K_CODES / 4, 256, 0, stream>>>(emb, esq);
    vq_main_kernel<<<N_ROWS / MT, BLOCK, 0, stream>>>(z, emb, esq, out, loss_acc);
    vq_finalize_kernel<<<1, 1, 0, stream>>>(loss_acc, out);
}